// Round 5
// baseline (2875.810 us; speedup 1.0000x reference)
//
#include <hip/hip_runtime.h>
#include <math.h>

#define SDIM 512
#define BDIM 64
#define HDIM 512
#define TDIM 32

#define G_BM 128
#define G_BN 128
#define G_KT 16
#define NJC  4   // HDIM / G_BN

// 4 partial-emission buffers (one per jc block-column), summed by viterbi.
// Layout: g_emp[jcb][(b*SDIM + s)*TDIM + tag]
__device__ float g_emp[NJC][SDIM * BDIM * TDIM];  // 16 MB

// ---------------- GEMM1 + sigmoid + GEMM2-partial ----------------
__global__ __launch_bounds__(256, 3) void emis_kernel(
    const float* __restrict__ hidden, const float* __restrict__ W1,
    const float* __restrict__ b1, const float* __restrict__ W2,
    const float* __restrict__ b2)
{
  __shared__ float As[2][G_KT][G_BM + 4];  // [k][r], padded to 132
  __shared__ float Bs[2][G_KT][G_BN];      // [k][c]
  __shared__ float W2cT[TDIM][G_BN];       // [t][c_local]

  const int tid = threadIdx.x;
  const int row0 = blockIdx.x * G_BM;
  const int jc   = blockIdx.y * G_BN;
  const int jcb  = blockIdx.y;

  const int tcg = tid & 15;   // col group: in-wave (lane&15) -> shfl-reducible
  const int trg = tid >> 4;   // row group 0..15

  // stage W2 slice transposed (visible after first __syncthreads below)
#pragma unroll
  for (int i = 0; i < 16; ++i) {
    int e = tid + 256 * i;  // 0..4095
    int j = e >> 5, t = e & 31;
    W2cT[t][j] = W2[(size_t)(jc + j) * TDIM + t];
  }

  float acc[2][2][4][4];
#pragma unroll
  for (int a = 0; a < 2; ++a)
#pragma unroll
    for (int c = 0; c < 2; ++c)
#pragma unroll
      for (int i = 0; i < 4; ++i)
#pragma unroll
        for (int j = 0; j < 4; ++j) acc[a][c][i][j] = 0.f;

  float4 a_st[2], b_st[2];

#define LOAD_STAGE(kc_)                                                        \
  {                                                                            \
    int k0 = (kc_)*G_KT;                                                       \
    _Pragma("unroll")                                                          \
    for (int i = 0; i < 2; ++i) {                                              \
      int f4 = tid + 256 * i;                                                  \
      int r = f4 >> 2, q = f4 & 3;                                             \
      a_st[i] = *(const float4*)&hidden[(size_t)(row0 + r) * HDIM + k0 + 4*q]; \
      int k = f4 >> 5, c4 = f4 & 31;                                           \
      b_st[i] = *(const float4*)&W1[(size_t)(k0 + k) * HDIM + jc + 4 * c4];    \
    }                                                                          \
  }

#define WRITE_STAGE(buf_)                                                      \
  {                                                                            \
    _Pragma("unroll")                                                          \
    for (int i = 0; i < 2; ++i) {                                              \
      int f4 = tid + 256 * i;                                                  \
      int r = f4 >> 2, q = f4 & 3;                                             \
      As[buf_][4 * q + 0][r] = a_st[i].x;                                      \
      As[buf_][4 * q + 1][r] = a_st[i].y;                                      \
      As[buf_][4 * q + 2][r] = a_st[i].z;                                      \
      As[buf_][4 * q + 3][r] = a_st[i].w;                                      \
      int k = f4 >> 5, c4 = f4 & 31;                                           \
      *(float4*)&Bs[buf_][k][4 * c4] = b_st[i];                                \
    }                                                                          \
  }

  LOAD_STAGE(0)
  WRITE_STAGE(0)
  __syncthreads();

  const int NKC = HDIM / G_KT;  // 32
  for (int kc = 0; kc < NKC; ++kc) {
    const int buf = kc & 1;
    if (kc + 1 < NKC) LOAD_STAGE(kc + 1)
#pragma unroll
    for (int kk = 0; kk < G_KT; ++kk) {
      float4 a0 = *(const float4*)&As[buf][kk][4 * trg];
      float4 a1 = *(const float4*)&As[buf][kk][64 + 4 * trg];
      float4 b0 = *(const float4*)&Bs[buf][kk][4 * tcg];
      float4 b1v = *(const float4*)&Bs[buf][kk][64 + 4 * tcg];
      float av[2][4] = {{a0.x, a0.y, a0.z, a0.w}, {a1.x, a1.y, a1.z, a1.w}};
      float bv[2][4] = {{b0.x, b0.y, b0.z, b0.w}, {b1v.x, b1v.y, b1v.z, b1v.w}};
#pragma unroll
      for (int ri = 0; ri < 2; ++ri)
#pragma unroll
        for (int i = 0; i < 4; ++i)
#pragma unroll
          for (int ci = 0; ci < 2; ++ci)
#pragma unroll
            for (int j = 0; j < 4; ++j)
              acc[ri][ci][i][j] = fmaf(av[ri][i], bv[ci][j], acc[ri][ci][i][j]);
    }
    if (kc + 1 < NKC) WRITE_STAGE((kc + 1) & 1)
    __syncthreads();
  }

  // bias + sigmoid (acc becomes h1)
#pragma unroll
  for (int ci = 0; ci < 2; ++ci) {
    float4 bb4 = *(const float4*)&b1[jc + 64 * ci + 4 * tcg];
    float bb[4] = {bb4.x, bb4.y, bb4.z, bb4.w};
#pragma unroll
    for (int ri = 0; ri < 2; ++ri)
#pragma unroll
      for (int i = 0; i < 4; ++i)
#pragma unroll
        for (int j = 0; j < 4; ++j)
          acc[ri][ci][i][j] = 1.f / (1.f + expf(-(acc[ri][ci][i][j] + bb[j])));
  }

  // GEMM2 partial: em_p[row][t] = sum_{c in this 128-col slice} h1*W2
  // reduce across the 16 tcg lanes (lane&15) via shfl_xor; writer lane stores.
#pragma unroll
  for (int tc = 0; tc < 8; ++tc) {
    float w[4][2][4];
#pragma unroll
    for (int tt = 0; tt < 4; ++tt)
#pragma unroll
      for (int ci = 0; ci < 2; ++ci) {
        float4 wv = *(const float4*)&W2cT[4 * tc + tt][64 * ci + 4 * tcg];
        w[tt][ci][0] = wv.x; w[tt][ci][1] = wv.y;
        w[tt][ci][2] = wv.z; w[tt][ci][3] = wv.w;
      }
    float em_e[2][4][4];  // [ri][i][tt]
#pragma unroll
    for (int ri = 0; ri < 2; ++ri)
#pragma unroll
      for (int i = 0; i < 4; ++i)
#pragma unroll
        for (int tt = 0; tt < 4; ++tt) em_e[ri][i][tt] = 0.f;
#pragma unroll
    for (int ri = 0; ri < 2; ++ri)
#pragma unroll
      for (int i = 0; i < 4; ++i)
#pragma unroll
        for (int tt = 0; tt < 4; ++tt)
#pragma unroll
          for (int ci = 0; ci < 2; ++ci)
#pragma unroll
            for (int j = 0; j < 4; ++j)
              em_e[ri][i][tt] = fmaf(acc[ri][ci][i][j], w[tt][ci][j], em_e[ri][i][tt]);
    // in-wave reduction over tcg (xor on lane bits 0..3)
#pragma unroll
    for (int off = 1; off < 16; off <<= 1)
#pragma unroll
      for (int ri = 0; ri < 2; ++ri)
#pragma unroll
        for (int i = 0; i < 4; ++i)
#pragma unroll
          for (int tt = 0; tt < 4; ++tt)
            em_e[ri][i][tt] += __shfl_xor(em_e[ri][i][tt], off, 64);

    if (tcg == tc) {
      float4 b2v = make_float4(0.f, 0.f, 0.f, 0.f);
      if (jcb == 0) b2v = *(const float4*)&b2[4 * tc];
#pragma unroll
      for (int ri = 0; ri < 2; ++ri)
#pragma unroll
        for (int i = 0; i < 4; ++i) {
          int grow = row0 + 64 * ri + 4 * trg + i;
          int s = grow >> 6, bb_ = grow & 63;
          float4 v;
          v.x = em_e[ri][i][0] + b2v.x;
          v.y = em_e[ri][i][1] + b2v.y;
          v.z = em_e[ri][i][2] + b2v.z;
          v.w = em_e[ri][i][3] + b2v.w;
          *(float4*)&g_emp[jcb][((size_t)bb_ * SDIM + s) * TDIM + 4 * tc] = v;
        }
    }
  }
#undef LOAD_STAGE
#undef WRITE_STAGE
}

// ---------------- Viterbi (1 wave / batch) ----------------
__global__ __launch_bounds__(64, 1) void viterbi_kernel(
    const int* __restrict__ lens, const float* __restrict__ trans,
    float* __restrict__ out)
{
  __shared__ float em[SDIM][TDIM];           // 64 KB
  __shared__ unsigned char bps[SDIM][TDIM];  // 16 KB
  const int b = blockIdx.x;
  const int lane = threadIdx.x;
  const int curr = lane & 31;
  const int h = lane >> 5;  // half: p in [16h, 16h+16)

  // bulk-stage emissions: sum of 4 partials
  {
    const float* p0 = g_emp[0] + (size_t)b * SDIM * TDIM;
    const float* p1 = g_emp[1] + (size_t)b * SDIM * TDIM;
    const float* p2 = g_emp[2] + (size_t)b * SDIM * TDIM;
    const float* p3 = g_emp[3] + (size_t)b * SDIM * TDIM;
    float* emf = &em[0][0];
#pragma unroll 4
    for (int piece = 0; piece < 64; ++piece) {
      int idx = piece * 256 + lane * 4;
      float4 v0 = *(const float4*)(p0 + idx);
      float4 v1 = *(const float4*)(p1 + idx);
      float4 v2 = *(const float4*)(p2 + idx);
      float4 v3 = *(const float4*)(p3 + idx);
      float4 s;
      s.x = (v0.x + v1.x) + (v2.x + v3.x);
      s.y = (v0.y + v1.y) + (v2.y + v3.y);
      s.z = (v0.z + v1.z) + (v2.z + v3.z);
      s.w = (v0.w + v1.w) + (v2.w + v3.w);
      *(float4*)(emf + idx) = s;
    }
  }
  __syncthreads();

  float tr[16];
#pragma unroll
  for (int p = 0; p < 16; ++p) tr[p] = trans[curr * TDIM + 16 * h + p];

  // int32/int64-robust lens (values >= 1 -> an int64 high word is 0)
  int len;
  {
    const int* p32 = lens;
    len = (p32[1] == 0) ? (int)((const long long*)lens)[b] : p32[b];
  }

  float fv = em[0][curr];
  float emn = em[1][curr];

  for (int t = 1; t < SDIM; ++t) {
    float emt = emn;
    int tn = (t < SDIM - 1) ? t + 1 : t;
    emn = em[tn][curr];

    float sv[16];
#pragma unroll
    for (int p = 0; p < 16; ++p)
      sv[p] = __shfl(fv, 16 * h + p, 64) + tr[p];

    // 4 chains of 4 (lowest-global-p wins ties), then ordered merge
    float c0 = sv[0], c1 = sv[4], c2 = sv[8], c3 = sv[12];
    int i0 = 16 * h + 0, i1 = 16 * h + 4, i2 = 16 * h + 8, i3 = 16 * h + 12;
#pragma unroll
    for (int m = 1; m < 4; ++m) {
      if (sv[m]      > c0) { c0 = sv[m];      i0 = 16 * h + m; }
      if (sv[4 + m]  > c1) { c1 = sv[4 + m];  i1 = 16 * h + 4 + m; }
      if (sv[8 + m]  > c2) { c2 = sv[8 + m];  i2 = 16 * h + 8 + m; }
      if (sv[12 + m] > c3) { c3 = sv[12 + m]; i3 = 16 * h + 12 + m; }
    }
    if (c1 > c0) { c0 = c1; i0 = i1; }
    if (c2 > c0) { c0 = c2; i0 = i2; }
    if (c3 > c0) { c0 = c3; i0 = i3; }

    // cross-half merge (symmetric; lower global index wins ties)
    float oc = __shfl_xor(c0, 32, 64);
    int   oi = __shfl_xor(i0, 32, 64);
    if (oc > c0 || (oc == c0 && oi < i0)) { c0 = oc; i0 = oi; }

    const bool active = (t < len);
    fv = active ? (c0 + emt) : fv;
    int bp = active ? i0 : curr;
    if (h == 0) bps[t][curr] = (unsigned char)bp;
  }

  // argmax over tags (lanes 0..31 hold fv; lowest index wins)
  float bs = fv;
  int bi = curr;
#pragma unroll
  for (int off = 16; off > 0; off >>= 1) {
    float os = __shfl_down(bs, off, 32);
    int oi = __shfl_down(bi, off, 32);
    if (os > bs || (os == bs && oi < bi)) { bs = os; bi = oi; }
  }
  bs = __shfl(bs, 0, 64);
  int tag = __shfl(bi, 0, 64);

  __syncthreads();  // bps fully written before backtrack reads

  if (lane == 0) {
    out[(size_t)SDIM * BDIM + b] = bs;
    out[(size_t)(SDIM - 1) * BDIM + b] = (float)tag;
  }

  // backtrack: prefetched row values + shfl chain (all lanes track tag)
  for (int t = SDIM - 1; t >= 1; t -= 4) {
    int r0v = bps[t][curr];
    int r1v = (t - 1 >= 1) ? bps[t - 1][curr] : 0;
    int r2v = (t - 2 >= 1) ? bps[t - 2][curr] : 0;
    int r3v = (t - 3 >= 1) ? bps[t - 3][curr] : 0;
    tag = __shfl(r0v, tag, 64);
    if (lane == 0) out[(size_t)(t - 1) * BDIM + b] = (float)tag;
    if (t - 1 >= 1) {
      tag = __shfl(r1v, tag, 64);
      if (lane == 0) out[(size_t)(t - 2) * BDIM + b] = (float)tag;
    }
    if (t - 2 >= 1) {
      tag = __shfl(r2v, tag, 64);
      if (lane == 0) out[(size_t)(t - 3) * BDIM + b] = (float)tag;
    }
    if (t - 3 >= 1) {
      tag = __shfl(r3v, tag, 64);
      if (lane == 0) out[(size_t)(t - 4) * BDIM + b] = (float)tag;
    }
  }
}

// ---------------- host ----------------
static int find_by_size(const int* in_sizes, int n_in, int sz, int fb) {
  for (int i = 0; i < n_in; ++i) if (in_sizes[i] == sz) return i;
  return fb;
}

extern "C" void kernel_launch(void* const* d_in, const int* in_sizes, int n_in,
                              void* d_out, int out_size, void* d_ws, size_t ws_size,
                              hipStream_t stream) {
  const int i_hidden = find_by_size(in_sizes, n_in, SDIM * BDIM * HDIM, 0);
  const int i_lens   = find_by_size(in_sizes, n_in, BDIM, 1);
  const int i_W1     = find_by_size(in_sizes, n_in, HDIM * HDIM, 3);
  const int i_b1     = find_by_size(in_sizes, n_in, HDIM, 4);
  const int i_W2     = find_by_size(in_sizes, n_in, HDIM * TDIM, 5);
  const int i_b2     = find_by_size(in_sizes, n_in, TDIM, 6);
  const int i_tr     = find_by_size(in_sizes, n_in, TDIM * TDIM, 7);

  const float* hidden = (const float*)d_in[i_hidden];
  const int*   lens   = (const int*)d_in[i_lens];
  const float* W1     = (const float*)d_in[i_W1];
  const float* b1     = (const float*)d_in[i_b1];
  const float* W2     = (const float*)d_in[i_W2];
  const float* b2     = (const float*)d_in[i_b2];
  const float* trans  = (const float*)d_in[i_tr];
  float* out = (float*)d_out;

  emis_kernel<<<dim3(SDIM * BDIM / G_BM, NJC), 256, 0, stream>>>(hidden, W1, b1, W2, b2);
  viterbi_kernel<<<BDIM, 64, 0, stream>>>(lens, trans, out);
}

// Round 6
// 543.316 us; speedup vs baseline: 5.2931x; 5.2931x over previous
//
#include <hip/hip_runtime.h>
#include <math.h>

#define SDIM 512
#define BDIM 64
#define HDIM 512
#define TDIM 32

#define G_BM 64    // one timestep (all 64 batch rows) per block
#define G_BN 128
#define G_KT 16
#define NJC  4     // HDIM / G_BN

// emissions, b-major for viterbi bulk staging: g_em[(b*SDIM + s)*TDIM + t]
__device__ float g_em[SDIM * BDIM * TDIM];  // 4 MB

// ---------------- GEMM1 + sigmoid + GEMM2 (fused, low-register) ----------------
__global__ __launch_bounds__(256, 2) void emis_kernel(
    const float* __restrict__ hidden, const float* __restrict__ W1,
    const float* __restrict__ b1, const float* __restrict__ W2,
    const float* __restrict__ b2)
{
  __shared__ float As[2][G_KT][G_BM + 4];   // [k][r]  8.7 KB
  __shared__ float Bs[2][G_KT][G_BN];       // [k][c]  16 KB
  __shared__ float H1[G_BM][G_BN + 4];      // 33.8 KB
  __shared__ float W2cT[TDIM][G_BN + 4];    // 16.9 KB   total 75.8 KB -> 2 blocks/CU

  const int tid = threadIdx.x;
  const int s = blockIdx.x;            // timestep
  const int row0 = s * G_BM;           // row in flattened [S*B, H]
  const int trow = tid & 15;           // 16 groups x 4 rows
  const int tcol = tid >> 4;           // 16 groups x 8 cols
  const int tx = tid & 31;             // tag lane (GEMM2 phase)
  const int ty = tid >> 5;             // row sub   (GEMM2 phase)

  float eacc[8];
#pragma unroll
  for (int k = 0; k < 8; ++k) eacc[k] = 0.f;

  float4 a_st, b_st[2];

#define LOAD_STAGE(kc_)                                                         \
  {                                                                             \
    const int k0 = (kc_)*G_KT;                                                  \
    { int r = tid >> 2, q = tid & 3;                                            \
      a_st = *(const float4*)&hidden[(size_t)(row0 + r) * HDIM + k0 + 4 * q]; } \
    _Pragma("unroll")                                                           \
    for (int i = 0; i < 2; ++i) {                                               \
      int f4 = tid + 256 * i;                                                   \
      int k = f4 >> 5, c4 = f4 & 31;                                            \
      b_st[i] = *(const float4*)&W1[(size_t)(k0 + k) * HDIM + jc + 4 * c4];     \
    }                                                                           \
  }

#define WRITE_STAGE(buf_)                                                       \
  {                                                                             \
    { int r = tid >> 2, q = tid & 3;                                            \
      As[buf_][4 * q + 0][r] = a_st.x;                                          \
      As[buf_][4 * q + 1][r] = a_st.y;                                          \
      As[buf_][4 * q + 2][r] = a_st.z;                                          \
      As[buf_][4 * q + 3][r] = a_st.w; }                                        \
    _Pragma("unroll")                                                           \
    for (int i = 0; i < 2; ++i) {                                               \
      int f4 = tid + 256 * i;                                                   \
      int k = f4 >> 5, c4 = f4 & 31;                                            \
      *(float4*)&Bs[buf_][k][4 * c4] = b_st[i];                                 \
    }                                                                           \
  }

  for (int jcb = 0; jcb < NJC; ++jcb) {
    const int jc = jcb * G_BN;

    // stage W2 slice transposed (LDS safe: barrier at end of prev chunk;
    // visible to GEMM2 after the K-loop barriers)
#pragma unroll
    for (int i = 0; i < 16; ++i) {
      int e = tid + 256 * i;  // 0..4095
      int j = e >> 5, t = e & 31;
      W2cT[t][j] = W2[(size_t)(jc + j) * TDIM + t];
    }

    float acc[4][8];
#pragma unroll
    for (int i = 0; i < 4; ++i)
#pragma unroll
      for (int j = 0; j < 8; ++j) acc[i][j] = 0.f;

    LOAD_STAGE(0)
    WRITE_STAGE(0)
    __syncthreads();

    const int NKC = HDIM / G_KT;  // 32
    for (int kc = 0; kc < NKC; ++kc) {
      const int buf = kc & 1;
      if (kc + 1 < NKC) LOAD_STAGE(kc + 1)
#pragma unroll
      for (int kk = 0; kk < G_KT; ++kk) {
        float4 a4 = *(const float4*)&As[buf][kk][4 * trow];
        float4 b40 = *(const float4*)&Bs[buf][kk][8 * tcol];
        float4 b41 = *(const float4*)&Bs[buf][kk][8 * tcol + 4];
        float av[4] = {a4.x, a4.y, a4.z, a4.w};
        float bv[8] = {b40.x, b40.y, b40.z, b40.w, b41.x, b41.y, b41.z, b41.w};
#pragma unroll
        for (int i = 0; i < 4; ++i)
#pragma unroll
          for (int j = 0; j < 8; ++j)
            acc[i][j] = fmaf(av[i], bv[j], acc[i][j]);
      }
      if (kc + 1 < NKC) WRITE_STAGE((kc + 1) & 1)
      __syncthreads();
    }

    // bias + sigmoid -> H1
    {
      float4 bb0 = *(const float4*)&b1[jc + 8 * tcol];
      float4 bb1 = *(const float4*)&b1[jc + 8 * tcol + 4];
      float bb[8] = {bb0.x, bb0.y, bb0.z, bb0.w, bb1.x, bb1.y, bb1.z, bb1.w};
#pragma unroll
      for (int i = 0; i < 4; ++i) {
        float4 h0, h1v;
        h0.x = 1.f / (1.f + expf(-(acc[i][0] + bb[0])));
        h0.y = 1.f / (1.f + expf(-(acc[i][1] + bb[1])));
        h0.z = 1.f / (1.f + expf(-(acc[i][2] + bb[2])));
        h0.w = 1.f / (1.f + expf(-(acc[i][3] + bb[3])));
        h1v.x = 1.f / (1.f + expf(-(acc[i][4] + bb[4])));
        h1v.y = 1.f / (1.f + expf(-(acc[i][5] + bb[5])));
        h1v.z = 1.f / (1.f + expf(-(acc[i][6] + bb[6])));
        h1v.w = 1.f / (1.f + expf(-(acc[i][7] + bb[7])));
        *(float4*)&H1[4 * trow + i][8 * tcol] = h0;
        *(float4*)&H1[4 * trow + i][8 * tcol + 4] = h1v;
      }
    }
    __syncthreads();

    // GEMM2 accumulate: eacc[k] += sum_j H1[ty+8k][j] * W2cT[tx][j]
#pragma unroll
    for (int jq = 0; jq < G_BN / 4; ++jq) {
      float4 w = *(const float4*)&W2cT[tx][4 * jq];
#pragma unroll
      for (int k = 0; k < 8; ++k) {
        float4 h = *(const float4*)&H1[ty + 8 * k][4 * jq];
        eacc[k] = fmaf(h.x, w.x, fmaf(h.y, w.y, fmaf(h.z, w.z, fmaf(h.w, w.w, eacc[k]))));
      }
    }
    __syncthreads();  // protect H1/W2cT/As/Bs before next chunk
  }

  // store: b-major em layout; 32 tag lanes -> 128 B contiguous per (b,s)
#pragma unroll
  for (int k = 0; k < 8; ++k) {
    int r = ty + 8 * k;  // = batch index b
    g_em[((size_t)r * SDIM + s) * TDIM + tx] = eacc[k] + b2[tx];
  }
#undef LOAD_STAGE
#undef WRITE_STAGE
}

// ---------------- Viterbi (1 wave / batch) ----------------
__global__ __launch_bounds__(64, 1) void viterbi_kernel(
    const int* __restrict__ lens, const float* __restrict__ trans,
    float* __restrict__ out)
{
  __shared__ float em[SDIM][TDIM];           // 64 KB
  __shared__ unsigned char bps[SDIM][TDIM];  // 16 KB
  const int b = blockIdx.x;
  const int lane = threadIdx.x;
  const int curr = lane & 31;
  const int h = lane >> 5;  // half: prev range [16h, 16h+16)

  // bulk-stage this batch's emissions (contiguous 64 KB)
  {
    const float* p0 = g_em + (size_t)b * SDIM * TDIM;
    float* emf = &em[0][0];
#pragma unroll 4
    for (int piece = 0; piece < 64; ++piece) {
      int idx = piece * 256 + lane * 4;
      *(float4*)(emf + idx) = *(const float4*)(p0 + idx);
    }
  }
  __syncthreads();

  float tr[16];
#pragma unroll
  for (int p = 0; p < 16; ++p) tr[p] = trans[curr * TDIM + 16 * h + p];

  // int32/int64-robust lens (values >= 1 -> int64 high word is 0)
  int len;
  {
    const int* p32 = lens;
    len = (p32[1] == 0) ? (int)((const long long*)lens)[b] : p32[b];
  }

  float fv = em[0][curr];
  float emn = em[1][curr];

  for (int t = 1; t < SDIM; ++t) {
    float emt = emn;
    int tn = (t < SDIM - 1) ? t + 1 : t;
    emn = em[tn][curr];

    float sv[16];
#pragma unroll
    for (int p = 0; p < 16; ++p)
      sv[p] = __shfl(fv, 16 * h + p, 64) + tr[p];

    // 4 chains of 4 (lowest-global-p wins ties), ordered merge
    float c0 = sv[0], c1 = sv[4], c2 = sv[8], c3 = sv[12];
    int i0 = 16 * h + 0, i1 = 16 * h + 4, i2 = 16 * h + 8, i3 = 16 * h + 12;
#pragma unroll
    for (int m = 1; m < 4; ++m) {
      if (sv[m]      > c0) { c0 = sv[m];      i0 = 16 * h + m; }
      if (sv[4 + m]  > c1) { c1 = sv[4 + m];  i1 = 16 * h + 4 + m; }
      if (sv[8 + m]  > c2) { c2 = sv[8 + m];  i2 = 16 * h + 8 + m; }
      if (sv[12 + m] > c3) { c3 = sv[12 + m]; i3 = 16 * h + 12 + m; }
    }
    if (c1 > c0) { c0 = c1; i0 = i1; }
    if (c2 > c0) { c0 = c2; i0 = i2; }
    if (c3 > c0) { c0 = c3; i0 = i3; }

    // cross-half merge (lower global index wins ties)
    float oc = __shfl_xor(c0, 32, 64);
    int   oi = __shfl_xor(i0, 32, 64);
    if (oc > c0 || (oc == c0 && oi < i0)) { c0 = oc; i0 = oi; }

    const bool active = (t < len);
    fv = active ? (c0 + emt) : fv;
    int bp = active ? i0 : curr;
    if (h == 0) bps[t][curr] = (unsigned char)bp;
  }

  // argmax over tags (lowest index wins)
  float bs = fv;
  int bi = curr;
#pragma unroll
  for (int off = 16; off > 0; off >>= 1) {
    float os = __shfl_down(bs, off, 32);
    int oi = __shfl_down(bi, off, 32);
    if (os > bs || (os == bs && oi < bi)) { bs = os; bi = oi; }
  }
  bs = __shfl(bs, 0, 64);
  int tag = __shfl(bi, 0, 64);

  __syncthreads();

  if (lane == 0) {
    out[(size_t)SDIM * BDIM + b] = bs;
    out[(size_t)(SDIM - 1) * BDIM + b] = (float)tag;
  }

  // backtrack: prefetched rows + shfl chain
  for (int t = SDIM - 1; t >= 1; t -= 4) {
    int r0v = bps[t][curr];
    int r1v = (t - 1 >= 1) ? bps[t - 1][curr] : 0;
    int r2v = (t - 2 >= 1) ? bps[t - 2][curr] : 0;
    int r3v = (t - 3 >= 1) ? bps[t - 3][curr] : 0;
    tag = __shfl(r0v, tag, 64);
    if (lane == 0) out[(size_t)(t - 1) * BDIM + b] = (float)tag;
    if (t - 1 >= 1) {
      tag = __shfl(r1v, tag, 64);
      if (lane == 0) out[(size_t)(t - 2) * BDIM + b] = (float)tag;
    }
    if (t - 2 >= 1) {
      tag = __shfl(r2v, tag, 64);
      if (lane == 0) out[(size_t)(t - 3) * BDIM + b] = (float)tag;
    }
    if (t - 3 >= 1) {
      tag = __shfl(r3v, tag, 64);
      if (lane == 0) out[(size_t)(t - 4) * BDIM + b] = (float)tag;
    }
  }
}

// ---------------- host ----------------
static int find_by_size(const int* in_sizes, int n_in, int sz, int fb) {
  for (int i = 0; i < n_in; ++i) if (in_sizes[i] == sz) return i;
  return fb;
}

extern "C" void kernel_launch(void* const* d_in, const int* in_sizes, int n_in,
                              void* d_out, int out_size, void* d_ws, size_t ws_size,
                              hipStream_t stream) {
  const int i_hidden = find_by_size(in_sizes, n_in, SDIM * BDIM * HDIM, 0);
  const int i_lens   = find_by_size(in_sizes, n_in, BDIM, 1);
  const int i_W1     = find_by_size(in_sizes, n_in, HDIM * HDIM, 3);
  const int i_b1     = find_by_size(in_sizes, n_in, HDIM, 4);
  const int i_W2     = find_by_size(in_sizes, n_in, HDIM * TDIM, 5);
  const int i_b2     = find_by_size(in_sizes, n_in, TDIM, 6);
  const int i_tr     = find_by_size(in_sizes, n_in, TDIM * TDIM, 7);

  const float* hidden = (const float*)d_in[i_hidden];
  const int*   lens   = (const int*)d_in[i_lens];
  const float* W1     = (const float*)d_in[i_W1];
  const float* b1     = (const float*)d_in[i_b1];
  const float* W2     = (const float*)d_in[i_W2];
  const float* b2     = (const float*)d_in[i_b2];
  const float* trans  = (const float*)d_in[i_tr];
  float* out = (float*)d_out;

  emis_kernel<<<SDIM, 256, 0, stream>>>(hidden, W1, b1, W2, b2);
  viterbi_kernel<<<BDIM, 64, 0, stream>>>(lens, trans, out);
}

// Round 7
// 343.196 us; speedup vs baseline: 8.3795x; 1.5831x over previous
//
#include <hip/hip_runtime.h>
#include <math.h>

#define SDIM 512
#define BDIM 64
#define HDIM 512
#define TDIM 32
#define MTOT (SDIM * BDIM)  // 32768

typedef __attribute__((ext_vector_type(8))) short bf16x8;
typedef __attribute__((ext_vector_type(4))) float f32x4;

// static device scratch
__device__ unsigned short g_w1hT[HDIM * HDIM];  // W1^T hi  [n][k]
__device__ unsigned short g_w1lT[HDIM * HDIM];  // W1^T lo  [n][k]
__device__ float g_h1[(size_t)MTOT * HDIM];     // 64 MB f32 sigmoid output
__device__ float g_em[(size_t)MTOT * TDIM];     // 4 MB emissions, b-major

__device__ __forceinline__ unsigned short f2bf(float x) {
  union { float f; unsigned int u; } v; v.f = x;
  unsigned int r = v.u + 0x7FFFu + ((v.u >> 16) & 1u);  // RNE
  return (unsigned short)(r >> 16);
}
__device__ __forceinline__ float bf2f(unsigned short h) {
  union { float f; unsigned int u; } v; v.u = ((unsigned int)h) << 16; return v.f;
}

// ---------------- W1 split + transpose (tiny, one-time per call) ----------------
__global__ void split_w1_kernel(const float* __restrict__ W1) {
  const int n = blockIdx.x;            // 512
  const int k0 = threadIdx.x * 4;      // 128 threads x 4 k
  ushort4 h, l;
  float x;
  x = W1[(size_t)(k0 + 0) * HDIM + n]; h.x = f2bf(x); l.x = f2bf(x - bf2f(h.x));
  x = W1[(size_t)(k0 + 1) * HDIM + n]; h.y = f2bf(x); l.y = f2bf(x - bf2f(h.y));
  x = W1[(size_t)(k0 + 2) * HDIM + n]; h.z = f2bf(x); l.z = f2bf(x - bf2f(h.z));
  x = W1[(size_t)(k0 + 3) * HDIM + n]; h.w = f2bf(x); l.w = f2bf(x - bf2f(h.w));
  *(ushort4*)&g_w1hT[(size_t)n * HDIM + k0] = h;
  *(ushort4*)&g_w1lT[(size_t)n * HDIM + k0] = l;
}

// ---------------- GEMM1: h1 = sigmoid(hidden @ W1 + b1), bf16x2 MFMA ----------------
// 128x128 tile, 4 waves (64x64 each), BK=32, single-buffered LDS (41 KB -> 3 blocks/CU)
__global__ __launch_bounds__(256) void gemm1_kernel(
    const float* __restrict__ hidden, const float* __restrict__ b1) {
  __shared__ unsigned short lAh[128][40];  // [row][k], pad 40 (80 B = 5x16 aligned)
  __shared__ unsigned short lAl[128][40];
  __shared__ unsigned short lBh[128][40];  // [n_local][k]
  __shared__ unsigned short lBl[128][40];

  const int tid = threadIdx.x;
  const int jc = blockIdx.x * 128;    // N chunk (x fastest -> A tiles L2-shared)
  const int row0 = blockIdx.y * 128;  // M block
  const int wave = tid >> 6;
  const int lane = tid & 63;
  const int wr = (wave >> 1) * 64;
  const int wc = (wave & 1) * 64;
  const int l15 = lane & 15;
  const int l4 = lane >> 4;  // 0..3

  f32x4 acc[4][4];
#pragma unroll
  for (int i = 0; i < 4; ++i)
#pragma unroll
    for (int j = 0; j < 4; ++j) acc[i][j] = (f32x4)(0.f);

  for (int k0 = 0; k0 < HDIM; k0 += 32) {
    // stage A (f32 -> hi/lo bf16): 128 rows x 32 k
#pragma unroll
    for (int i = 0; i < 4; ++i) {
      int f4 = tid + 256 * i;        // 0..1023
      int r = f4 >> 3, kq = f4 & 7;  // 128 x 8 quads
      float4 v = *(const float4*)&hidden[(size_t)(row0 + r) * HDIM + k0 + 4 * kq];
      ushort4 h, l;
      h.x = f2bf(v.x); l.x = f2bf(v.x - bf2f(h.x));
      h.y = f2bf(v.y); l.y = f2bf(v.y - bf2f(h.y));
      h.z = f2bf(v.z); l.z = f2bf(v.z - bf2f(h.z));
      h.w = f2bf(v.w); l.w = f2bf(v.w - bf2f(h.w));
      *(ushort4*)&lAh[r][4 * kq] = h;
      *(ushort4*)&lAl[r][4 * kq] = l;
    }
    // stage B from pre-split W1^T: 128 n x 32 k (bf16 already)
#pragma unroll
    for (int i = 0; i < 2; ++i) {
      int f8 = tid + 256 * i;          // 0..511
      int nl = f8 >> 2, kq8 = f8 & 3;  // 128 x 4 octs
      *(uint4*)&lBh[nl][8 * kq8] =
          *(const uint4*)&g_w1hT[(size_t)(jc + nl) * HDIM + k0 + 8 * kq8];
      *(uint4*)&lBl[nl][8 * kq8] =
          *(const uint4*)&g_w1lT[(size_t)(jc + nl) * HDIM + k0 + 8 * kq8];
    }
    __syncthreads();

    // fragments: A lane layout row=l&15, k=(l>>4)*8+e ; B col=l&15, k=(l>>4)*8+e
    bf16x8 aH[4], aL[4];
#pragma unroll
    for (int i = 0; i < 4; ++i) {
      aH[i] = *(const bf16x8*)&lAh[wr + 16 * i + l15][8 * l4];
      aL[i] = *(const bf16x8*)&lAl[wr + 16 * i + l15][8 * l4];
    }
#pragma unroll
    for (int j = 0; j < 4; ++j) {
      bf16x8 bH = *(const bf16x8*)&lBh[wc + 16 * j + l15][8 * l4];
      bf16x8 bL = *(const bf16x8*)&lBl[wc + 16 * j + l15][8 * l4];
#pragma unroll
      for (int i = 0; i < 4; ++i) {
        acc[i][j] = __builtin_amdgcn_mfma_f32_16x16x32_bf16(aH[i], bH, acc[i][j], 0, 0, 0);
        acc[i][j] = __builtin_amdgcn_mfma_f32_16x16x32_bf16(aH[i], bL, acc[i][j], 0, 0, 0);
        acc[i][j] = __builtin_amdgcn_mfma_f32_16x16x32_bf16(aL[i], bH, acc[i][j], 0, 0, 0);
      }
    }
    __syncthreads();
  }

  // epilogue: bias + sigmoid -> f32 h1.  C/D layout: col=lane&15, row=(lane>>4)*4+r
#pragma unroll
  for (int j = 0; j < 4; ++j) {
    const int col = jc + wc + 16 * j + l15;
    const float bv = b1[col];
#pragma unroll
    for (int i = 0; i < 4; ++i) {
#pragma unroll
      for (int r = 0; r < 4; ++r) {
        int grow = row0 + wr + 16 * i + 4 * l4 + r;
        float h = 1.f / (1.f + expf(-(acc[i][j][r] + bv)));
        g_h1[(size_t)grow * HDIM + col] = h;
      }
    }
  }
}

// ---------------- GEMM2: em = h1 @ W2 + b2 (f32 vector, proven pattern) ----------------
__global__ __launch_bounds__(256) void gemm2_kernel(
    const float* __restrict__ W2, const float* __restrict__ b2) {
  __shared__ float H1s[64][132];
  __shared__ float W2cT[TDIM][132];
  const int tid = threadIdx.x;
  const int s = blockIdx.x;      // timestep
  const int row0 = s * 64;
  const int tx = tid & 31;       // tag
  const int ty = tid >> 5;       // 0..7

  float eacc[8];
#pragma unroll
  for (int k = 0; k < 8; ++k) eacc[k] = 0.f;

  for (int jcb = 0; jcb < 4; ++jcb) {
    const int jc = jcb * 128;
#pragma unroll
    for (int i = 0; i < 16; ++i) {
      int e = tid + 256 * i;  // 0..4095
      int j = e >> 5, t = e & 31;
      W2cT[t][j] = W2[(size_t)(jc + j) * TDIM + t];
    }
#pragma unroll
    for (int i = 0; i < 8; ++i) {
      int f4 = tid + 256 * i;         // 0..2047
      int r = f4 >> 5, cq = f4 & 31;  // 64 rows x 32 quads
      *(float4*)&H1s[r][4 * cq] = *(const float4*)&g_h1[(size_t)(row0 + r) * HDIM + jc + 4 * cq];
    }
    __syncthreads();
#pragma unroll
    for (int jq = 0; jq < 32; ++jq) {
      float4 w = *(const float4*)&W2cT[tx][4 * jq];
#pragma unroll
      for (int k = 0; k < 8; ++k) {
        float4 h = *(const float4*)&H1s[ty + 8 * k][4 * jq];
        eacc[k] = fmaf(h.x, w.x, fmaf(h.y, w.y, fmaf(h.z, w.z, fmaf(h.w, w.w, eacc[k]))));
      }
    }
    __syncthreads();
  }

#pragma unroll
  for (int k = 0; k < 8; ++k) {
    int b = ty + 8 * k;  // row = s*64 + b
    g_em[((size_t)b * SDIM + s) * TDIM + tx] = eacc[k] + b2[tx];
  }
}

// ---------------- Viterbi (1 wave / batch) — unchanged from round 6 ----------------
__global__ __launch_bounds__(64, 1) void viterbi_kernel(
    const int* __restrict__ lens, const float* __restrict__ trans,
    float* __restrict__ out) {
  __shared__ float em[SDIM][TDIM];
  __shared__ unsigned char bps[SDIM][TDIM];
  const int b = blockIdx.x;
  const int lane = threadIdx.x;
  const int curr = lane & 31;
  const int h = lane >> 5;

  {
    const float* p0 = g_em + (size_t)b * SDIM * TDIM;
    float* emf = &em[0][0];
#pragma unroll 4
    for (int piece = 0; piece < 64; ++piece) {
      int idx = piece * 256 + lane * 4;
      *(float4*)(emf + idx) = *(const float4*)(p0 + idx);
    }
  }
  __syncthreads();

  float tr[16];
#pragma unroll
  for (int p = 0; p < 16; ++p) tr[p] = trans[curr * TDIM + 16 * h + p];

  int len;
  {
    const int* p32 = lens;
    len = (p32[1] == 0) ? (int)((const long long*)lens)[b] : p32[b];
  }

  float fv = em[0][curr];
  float emn = em[1][curr];

  for (int t = 1; t < SDIM; ++t) {
    float emt = emn;
    int tn = (t < SDIM - 1) ? t + 1 : t;
    emn = em[tn][curr];

    float sv[16];
#pragma unroll
    for (int p = 0; p < 16; ++p)
      sv[p] = __shfl(fv, 16 * h + p, 64) + tr[p];

    float c0 = sv[0], c1 = sv[4], c2 = sv[8], c3 = sv[12];
    int i0 = 16 * h + 0, i1 = 16 * h + 4, i2 = 16 * h + 8, i3 = 16 * h + 12;
#pragma unroll
    for (int m = 1; m < 4; ++m) {
      if (sv[m]      > c0) { c0 = sv[m];      i0 = 16 * h + m; }
      if (sv[4 + m]  > c1) { c1 = sv[4 + m];  i1 = 16 * h + 4 + m; }
      if (sv[8 + m]  > c2) { c2 = sv[8 + m];  i2 = 16 * h + 8 + m; }
      if (sv[12 + m] > c3) { c3 = sv[12 + m]; i3 = 16 * h + 12 + m; }
    }
    if (c1 > c0) { c0 = c1; i0 = i1; }
    if (c2 > c0) { c0 = c2; i0 = i2; }
    if (c3 > c0) { c0 = c3; i0 = i3; }

    float oc = __shfl_xor(c0, 32, 64);
    int   oi = __shfl_xor(i0, 32, 64);
    if (oc > c0 || (oc == c0 && oi < i0)) { c0 = oc; i0 = oi; }

    const bool active = (t < len);
    fv = active ? (c0 + emt) : fv;
    int bp = active ? i0 : curr;
    if (h == 0) bps[t][curr] = (unsigned char)bp;
  }

  float bs = fv;
  int bi = curr;
#pragma unroll
  for (int off = 16; off > 0; off >>= 1) {
    float os = __shfl_down(bs, off, 32);
    int oi = __shfl_down(bi, off, 32);
    if (os > bs || (os == bs && oi < bi)) { bs = os; bi = oi; }
  }
  bs = __shfl(bs, 0, 64);
  int tag = __shfl(bi, 0, 64);

  __syncthreads();

  if (lane == 0) {
    out[(size_t)SDIM * BDIM + b] = bs;
    out[(size_t)(SDIM - 1) * BDIM + b] = (float)tag;
  }

  for (int t = SDIM - 1; t >= 1; t -= 4) {
    int r0v = bps[t][curr];
    int r1v = (t - 1 >= 1) ? bps[t - 1][curr] : 0;
    int r2v = (t - 2 >= 1) ? bps[t - 2][curr] : 0;
    int r3v = (t - 3 >= 1) ? bps[t - 3][curr] : 0;
    tag = __shfl(r0v, tag, 64);
    if (lane == 0) out[(size_t)(t - 1) * BDIM + b] = (float)tag;
    if (t - 1 >= 1) {
      tag = __shfl(r1v, tag, 64);
      if (lane == 0) out[(size_t)(t - 2) * BDIM + b] = (float)tag;
    }
    if (t - 2 >= 1) {
      tag = __shfl(r2v, tag, 64);
      if (lane == 0) out[(size_t)(t - 3) * BDIM + b] = (float)tag;
    }
    if (t - 3 >= 1) {
      tag = __shfl(r3v, tag, 64);
      if (lane == 0) out[(size_t)(t - 4) * BDIM + b] = (float)tag;
    }
  }
}

// ---------------- host ----------------
static int find_by_size(const int* in_sizes, int n_in, int sz, int fb) {
  for (int i = 0; i < n_in; ++i) if (in_sizes[i] == sz) return i;
  return fb;
}

extern "C" void kernel_launch(void* const* d_in, const int* in_sizes, int n_in,
                              void* d_out, int out_size, void* d_ws, size_t ws_size,
                              hipStream_t stream) {
  const int i_hidden = find_by_size(in_sizes, n_in, SDIM * BDIM * HDIM, 0);
  const int i_lens   = find_by_size(in_sizes, n_in, BDIM, 1);
  const int i_W1     = find_by_size(in_sizes, n_in, HDIM * HDIM, 3);
  const int i_b1     = find_by_size(in_sizes, n_in, HDIM, 4);
  const int i_W2     = find_by_size(in_sizes, n_in, HDIM * TDIM, 5);
  const int i_b2     = find_by_size(in_sizes, n_in, TDIM, 6);
  const int i_tr     = find_by_size(in_sizes, n_in, TDIM * TDIM, 7);

  const float* hidden = (const float*)d_in[i_hidden];
  const int*   lens   = (const int*)d_in[i_lens];
  const float* W1     = (const float*)d_in[i_W1];
  const float* b1     = (const float*)d_in[i_b1];
  const float* W2     = (const float*)d_in[i_W2];
  const float* b2     = (const float*)d_in[i_b2];
  const float* trans  = (const float*)d_in[i_tr];
  float* out = (float*)d_out;

  split_w1_kernel<<<HDIM, 128, 0, stream>>>(W1);
  gemm1_kernel<<<dim3(HDIM / 128, MTOT / 128), 256, 0, stream>>>(hidden, b1);
  gemm2_kernel<<<SDIM, 256, 0, stream>>>(W2, b2);
  viterbi_kernel<<<BDIM, 64, 0, stream>>>(lens, trans, out);
}

// Round 8
// 307.110 us; speedup vs baseline: 9.3641x; 1.1175x over previous
//
#include <hip/hip_runtime.h>
#include <math.h>

#define SDIM 512
#define BDIM 64
#define HDIM 512
#define TDIM 32
#define MTOT (SDIM * BDIM)

typedef __attribute__((ext_vector_type(8))) short bf16x8;
typedef __attribute__((ext_vector_type(4))) float f32x4;

// static device scratch
__device__ unsigned short g_w1hT[HDIM * HDIM];  // W1^T hi [n][k]
__device__ unsigned short g_w1lT[HDIM * HDIM];  // W1^T lo [n][k]
__device__ unsigned short g_w2hT[TDIM * HDIM];  // W2^T hi [t][k]
__device__ unsigned short g_w2lT[TDIM * HDIM];  // W2^T lo [t][k]
__device__ float g_em[(size_t)MTOT * TDIM];     // 4 MB emissions, b-major

__device__ __forceinline__ unsigned short f2bf(float x) {
  union { float f; unsigned int u; } v; v.f = x;
  unsigned int r = v.u + 0x7FFFu + ((v.u >> 16) & 1u);  // RNE
  return (unsigned short)(r >> 16);
}
__device__ __forceinline__ float bf2f(unsigned short h) {
  union { float f; unsigned int u; } v; v.u = ((unsigned int)h) << 16; return v.f;
}

// ---------------- W1/W2 split + transpose ----------------
__global__ void split_kernel(const float* __restrict__ W1, const float* __restrict__ W2) {
  const int n = blockIdx.x;
  const int k0 = threadIdx.x * 4;
  if (n < HDIM) {  // W1 column n
    ushort4 h, l; float x;
    x = W1[(size_t)(k0 + 0) * HDIM + n]; h.x = f2bf(x); l.x = f2bf(x - bf2f(h.x));
    x = W1[(size_t)(k0 + 1) * HDIM + n]; h.y = f2bf(x); l.y = f2bf(x - bf2f(h.y));
    x = W1[(size_t)(k0 + 2) * HDIM + n]; h.z = f2bf(x); l.z = f2bf(x - bf2f(h.z));
    x = W1[(size_t)(k0 + 3) * HDIM + n]; h.w = f2bf(x); l.w = f2bf(x - bf2f(h.w));
    *(ushort4*)&g_w1hT[(size_t)n * HDIM + k0] = h;
    *(ushort4*)&g_w1lT[(size_t)n * HDIM + k0] = l;
  } else {         // W2 column (tag) n-512
    const int t = n - HDIM;
    ushort4 h, l; float x;
    x = W2[(size_t)(k0 + 0) * TDIM + t]; h.x = f2bf(x); l.x = f2bf(x - bf2f(h.x));
    x = W2[(size_t)(k0 + 1) * TDIM + t]; h.y = f2bf(x); l.y = f2bf(x - bf2f(h.y));
    x = W2[(size_t)(k0 + 2) * TDIM + t]; h.z = f2bf(x); l.z = f2bf(x - bf2f(h.z));
    x = W2[(size_t)(k0 + 3) * TDIM + t]; h.w = f2bf(x); l.w = f2bf(x - bf2f(h.w));
    *(ushort4*)&g_w2hT[(size_t)t * HDIM + k0] = h;
    *(ushort4*)&g_w2lT[(size_t)t * HDIM + k0] = l;
  }
}

// ---------------- Fused emissions: MFMA GEMM1 + sigmoid(hi/lo) + MFMA GEMM2 ----------------
// block = 64 rows (one timestep), 4 waves; jc loop over 4 chunks of 128 h1-cols.
__global__ __launch_bounds__(256) void emis_kernel(
    const float* __restrict__ hidden, const float* __restrict__ b1,
    const float* __restrict__ b2)
{
  __shared__ unsigned short lAh[64][40];    // 5.1 KB
  __shared__ unsigned short lAl[64][40];
  __shared__ unsigned short lBh[128][40];   // 10.25 KB
  __shared__ unsigned short lBl[128][40];
  __shared__ unsigned short H1h[64][136];   // 17.4 KB
  __shared__ unsigned short H1l[64][136];   // total ~65.6 KB -> 2 blocks/CU

  const int tid = threadIdx.x;
  const int s = blockIdx.x;          // timestep
  const int row0 = s * 64;
  const int wave = tid >> 6;
  const int lane = tid & 63;
  const int l15 = lane & 15;
  const int l4 = lane >> 4;          // 0..3
  const int wr1 = (wave >> 1) * 32;  // GEMM1 row offset
  const int wc1 = (wave & 1) * 64;   // GEMM1 col offset

  f32x4 acc_em[2];
  acc_em[0] = (f32x4)(0.f);
  acc_em[1] = (f32x4)(0.f);

  for (int jcb = 0; jcb < 4; ++jcb) {
    const int jc = jcb * 128;

    f32x4 acc1[2][4];
#pragma unroll
    for (int i = 0; i < 2; ++i)
#pragma unroll
      for (int j = 0; j < 4; ++j) acc1[i][j] = (f32x4)(0.f);

    for (int k0 = 0; k0 < HDIM; k0 += 32) {
      // stage A: 64 rows x 32 k, f32 -> hi/lo
#pragma unroll
      for (int i = 0; i < 2; ++i) {
        int f4 = tid + 256 * i;        // 0..511
        int r = f4 >> 3, q = f4 & 7;
        float4 v = *(const float4*)&hidden[(size_t)(row0 + r) * HDIM + k0 + 4 * q];
        ushort4 h, l;
        h.x = f2bf(v.x); l.x = f2bf(v.x - bf2f(h.x));
        h.y = f2bf(v.y); l.y = f2bf(v.y - bf2f(h.y));
        h.z = f2bf(v.z); l.z = f2bf(v.z - bf2f(h.z));
        h.w = f2bf(v.w); l.w = f2bf(v.w - bf2f(h.w));
        *(ushort4*)&lAh[r][4 * q] = h;
        *(ushort4*)&lAl[r][4 * q] = l;
      }
      // stage B: 128 n x 32 k from pre-split W1^T
#pragma unroll
      for (int i = 0; i < 2; ++i) {
        int f8 = tid + 256 * i;          // 0..511
        int nl = f8 >> 2, kq8 = f8 & 3;
        *(uint4*)&lBh[nl][8 * kq8] =
            *(const uint4*)&g_w1hT[(size_t)(jc + nl) * HDIM + k0 + 8 * kq8];
        *(uint4*)&lBl[nl][8 * kq8] =
            *(const uint4*)&g_w1lT[(size_t)(jc + nl) * HDIM + k0 + 8 * kq8];
      }
      __syncthreads();

      bf16x8 aH[2], aL[2];
#pragma unroll
      for (int i = 0; i < 2; ++i) {
        aH[i] = *(const bf16x8*)&lAh[wr1 + 16 * i + l15][8 * l4];
        aL[i] = *(const bf16x8*)&lAl[wr1 + 16 * i + l15][8 * l4];
      }
#pragma unroll
      for (int j = 0; j < 4; ++j) {
        bf16x8 bH = *(const bf16x8*)&lBh[wc1 + 16 * j + l15][8 * l4];
        bf16x8 bL = *(const bf16x8*)&lBl[wc1 + 16 * j + l15][8 * l4];
#pragma unroll
        for (int i = 0; i < 2; ++i) {
          acc1[i][j] = __builtin_amdgcn_mfma_f32_16x16x32_bf16(aH[i], bH, acc1[i][j], 0, 0, 0);
          acc1[i][j] = __builtin_amdgcn_mfma_f32_16x16x32_bf16(aH[i], bL, acc1[i][j], 0, 0, 0);
          acc1[i][j] = __builtin_amdgcn_mfma_f32_16x16x32_bf16(aL[i], bH, acc1[i][j], 0, 0, 0);
        }
      }
      __syncthreads();
    }

    // epilogue: bias + sigmoid -> hi/lo bf16 into H1
#pragma unroll
    for (int j = 0; j < 4; ++j) {
      const int col = wc1 + 16 * j + l15;  // chunk-local h1 col
      const float bv = b1[jc + col];
#pragma unroll
      for (int i = 0; i < 2; ++i) {
#pragma unroll
        for (int r = 0; r < 4; ++r) {
          int lrow = wr1 + 16 * i + 4 * l4 + r;
          float h = 1.f / (1.f + expf(-(acc1[i][j][r] + bv)));
          unsigned short hh = f2bf(h);
          unsigned short hl = f2bf(h - bf2f(hh));
          H1h[lrow][col] = hh;
          H1l[lrow][col] = hl;
        }
      }
    }
    __syncthreads();

    // GEMM2 partial: wave owns rows 16*wave..+15; K = this 128-col chunk
#pragma unroll
    for (int ks = 0; ks < 4; ++ks) {
      bf16x8 aH2 = *(const bf16x8*)&H1h[16 * wave + l15][32 * ks + 8 * l4];
      bf16x8 aL2 = *(const bf16x8*)&H1l[16 * wave + l15][32 * ks + 8 * l4];
#pragma unroll
      for (int j2 = 0; j2 < 2; ++j2) {
        const size_t wo = (size_t)(16 * j2 + l15) * HDIM + jc + 32 * ks + 8 * l4;
        bf16x8 bH2 = *(const bf16x8*)&g_w2hT[wo];
        bf16x8 bL2 = *(const bf16x8*)&g_w2lT[wo];
        acc_em[j2] = __builtin_amdgcn_mfma_f32_16x16x32_bf16(aH2, bH2, acc_em[j2], 0, 0, 0);
        acc_em[j2] = __builtin_amdgcn_mfma_f32_16x16x32_bf16(aH2, bL2, acc_em[j2], 0, 0, 0);
        acc_em[j2] = __builtin_amdgcn_mfma_f32_16x16x32_bf16(aL2, bH2, acc_em[j2], 0, 0, 0);
      }
    }
    __syncthreads();
  }

  // em store: C/D col=l15 -> tag, row = 16*wave + 4*l4 + r -> batch b (row0 mult of 64)
#pragma unroll
  for (int j2 = 0; j2 < 2; ++j2) {
    const int t = 16 * j2 + l15;
    const float bv = b2[t];
#pragma unroll
    for (int r = 0; r < 4; ++r) {
      int b = 16 * wave + 4 * l4 + r;
      g_em[((size_t)b * SDIM + s) * TDIM + t] = acc_em[j2][r] + bv;
    }
  }
}

// ---------------- Viterbi: 1 wave = 2 chains (c-per-lane, zero-shfl inner loop) ----------------
__global__ __launch_bounds__(64) void viterbi_kernel(
    const int* __restrict__ lens, const float* __restrict__ trans,
    float* __restrict__ out)
{
  __shared__ float lds_fv[64];
  __shared__ unsigned char bps[2][SDIM][TDIM];  // 32 KB

  const int lane = threadIdx.x;
  const int c = lane & 31;
  const int chain = lane >> 5;
  const int b0 = 2 * blockIdx.x;
  const int b = b0 + chain;

  // transition row for this lane's curr tag: tr[p] = trans[c][p]
  float tr[TDIM];
#pragma unroll
  for (int p = 0; p < TDIM; p += 4) {
    float4 t4 = *(const float4*)&trans[c * TDIM + p];
    tr[p] = t4.x; tr[p + 1] = t4.y; tr[p + 2] = t4.z; tr[p + 3] = t4.w;
  }

  int len;
  {
    const int* p32 = lens;
    len = (p32[1] == 0) ? (int)((const long long*)lens)[b] : p32[b];
  }

  const float* em = g_em + (size_t)b * SDIM * TDIM;

  float fv = em[c];                 // t = 0
  float e_cur = em[TDIM + c];       // t = 1
  float e_nxt = em[2 * TDIM + c];   // t = 2

  lds_fv[lane] = fv;
  const float* fvbase = &lds_fv[chain * 32];

  for (int t = 1; t < SDIM; ++t) {
    // broadcast read of this chain's fv vector (same-addr across half: conflict-free)
    float4 q0 = *(const float4*)(fvbase + 0);
    float4 q1 = *(const float4*)(fvbase + 4);
    float4 q2 = *(const float4*)(fvbase + 8);
    float4 q3 = *(const float4*)(fvbase + 12);
    float4 q4 = *(const float4*)(fvbase + 16);
    float4 q5 = *(const float4*)(fvbase + 20);
    float4 q6 = *(const float4*)(fvbase + 24);
    float4 q7 = *(const float4*)(fvbase + 28);
    float sv[TDIM];
    sv[0] = q0.x + tr[0];  sv[1] = q0.y + tr[1];  sv[2] = q0.z + tr[2];  sv[3] = q0.w + tr[3];
    sv[4] = q1.x + tr[4];  sv[5] = q1.y + tr[5];  sv[6] = q1.z + tr[6];  sv[7] = q1.w + tr[7];
    sv[8] = q2.x + tr[8];  sv[9] = q2.y + tr[9];  sv[10] = q2.z + tr[10]; sv[11] = q2.w + tr[11];
    sv[12] = q3.x + tr[12]; sv[13] = q3.y + tr[13]; sv[14] = q3.z + tr[14]; sv[15] = q3.w + tr[15];
    sv[16] = q4.x + tr[16]; sv[17] = q4.y + tr[17]; sv[18] = q4.z + tr[18]; sv[19] = q4.w + tr[19];
    sv[20] = q5.x + tr[20]; sv[21] = q5.y + tr[21]; sv[22] = q5.z + tr[22]; sv[23] = q5.w + tr[23];
    sv[24] = q6.x + tr[24]; sv[25] = q6.y + tr[25]; sv[26] = q6.z + tr[26]; sv[27] = q6.w + tr[27];
    sv[28] = q7.x + tr[28]; sv[29] = q7.y + tr[29]; sv[30] = q7.z + tr[30]; sv[31] = q7.w + tr[31];

    // argmax over 32 candidates, lowest index wins: 8 chains of 4 + ordered merge
    float cv[8]; int ci[8];
#pragma unroll
    for (int g = 0; g < 8; ++g) {
      float v = sv[4 * g]; int ix = 4 * g;
      if (sv[4 * g + 1] > v) { v = sv[4 * g + 1]; ix = 4 * g + 1; }
      if (sv[4 * g + 2] > v) { v = sv[4 * g + 2]; ix = 4 * g + 2; }
      if (sv[4 * g + 3] > v) { v = sv[4 * g + 3]; ix = 4 * g + 3; }
      cv[g] = v; ci[g] = ix;
    }
    float m01 = cv[0]; int i01 = ci[0]; if (cv[1] > m01) { m01 = cv[1]; i01 = ci[1]; }
    float m23 = cv[2]; int i23 = ci[2]; if (cv[3] > m23) { m23 = cv[3]; i23 = ci[3]; }
    float m45 = cv[4]; int i45 = ci[4]; if (cv[5] > m45) { m45 = cv[5]; i45 = ci[5]; }
    float m67 = cv[6]; int i67 = ci[6]; if (cv[7] > m67) { m67 = cv[7]; i67 = ci[7]; }
    if (m23 > m01) { m01 = m23; i01 = i23; }
    if (m67 > m45) { m45 = m67; i45 = i67; }
    if (m45 > m01) { m01 = m45; i01 = i45; }

    const bool active = (t < len);
    fv = active ? (m01 + e_cur) : fv;
    int bp = active ? i01 : c;
    bps[chain][t][c] = (unsigned char)bp;
    lds_fv[lane] = fv;

    e_cur = e_nxt;
    int tn = (t + 2 < SDIM) ? t + 2 : SDIM - 1;
    e_nxt = em[(size_t)tn * TDIM + c];
  }

  // final argmax over c within each half (width-32 keeps chains separate)
  float bs = fv;
  int bi = c;
#pragma unroll
  for (int off = 16; off > 0; off >>= 1) {
    float os = __shfl_down(bs, off, 32);
    int oi = __shfl_down(bi, off, 32);
    if (os > bs || (os == bs && oi < bi)) { bs = os; bi = oi; }
  }
  bs = __shfl(bs, 0, 32);
  int tag = __shfl(bi, 0, 32);

  __syncthreads();

  if (c == 0) {
    out[(size_t)SDIM * BDIM + b] = bs;
    out[(size_t)(SDIM - 1) * BDIM + b] = (float)tag;
  }

  // backtrack: both chains via one bpermute per step; prefetch 4 rows
  for (int t = SDIM - 1; t >= 1; t -= 4) {
    int r0v = bps[chain][t][c];
    int r1v = (t - 1 >= 1) ? bps[chain][t - 1][c] : 0;
    int r2v = (t - 2 >= 1) ? bps[chain][t - 2][c] : 0;
    int r3v = (t - 3 >= 1) ? bps[chain][t - 3][c] : 0;
    tag = __shfl(r0v, (lane & 32) | tag, 64);
    if (c == 0) out[(size_t)(t - 1) * BDIM + b] = (float)tag;
    if (t - 1 >= 1) {
      tag = __shfl(r1v, (lane & 32) | tag, 64);
      if (c == 0) out[(size_t)(t - 2) * BDIM + b] = (float)tag;
    }
    if (t - 2 >= 1) {
      tag = __shfl(r2v, (lane & 32) | tag, 64);
      if (c == 0) out[(size_t)(t - 3) * BDIM + b] = (float)tag;
    }
    if (t - 3 >= 1) {
      tag = __shfl(r3v, (lane & 32) | tag, 64);
      if (c == 0) out[(size_t)(t - 4) * BDIM + b] = (float)tag;
    }
  }
}

// ---------------- host ----------------
static int find_by_size(const int* in_sizes, int n_in, int sz, int fb) {
  for (int i = 0; i < n_in; ++i) if (in_sizes[i] == sz) return i;
  return fb;
}

extern "C" void kernel_launch(void* const* d_in, const int* in_sizes, int n_in,
                              void* d_out, int out_size, void* d_ws, size_t ws_size,
                              hipStream_t stream) {
  const int i_hidden = find_by_size(in_sizes, n_in, SDIM * BDIM * HDIM, 0);
  const int i_lens   = find_by_size(in_sizes, n_in, BDIM, 1);
  const int i_W1     = find_by_size(in_sizes, n_in, HDIM * HDIM, 3);
  const int i_b1     = find_by_size(in_sizes, n_in, HDIM, 4);
  const int i_W2     = find_by_size(in_sizes, n_in, HDIM * TDIM, 5);
  const int i_b2     = find_by_size(in_sizes, n_in, TDIM, 6);
  const int i_tr     = find_by_size(in_sizes, n_in, TDIM * TDIM, 7);

  const float* hidden = (const float*)d_in[i_hidden];
  const int*   lens   = (const int*)d_in[i_lens];
  const float* W1     = (const float*)d_in[i_W1];
  const float* b1     = (const float*)d_in[i_b1];
  const float* W2     = (const float*)d_in[i_W2];
  const float* b2     = (const float*)d_in[i_b2];
  const float* trans  = (const float*)d_in[i_tr];
  float* out = (float*)d_out;

  split_kernel<<<HDIM + TDIM, 128, 0, stream>>>(W1, W2);
  emis_kernel<<<SDIM, 256, 0, stream>>>(hidden, b1, b2);
  viterbi_kernel<<<BDIM / 2, 64, 0, stream>>>(lens, trans, out);
}